// Round 11
// baseline (621.813 us; speedup 1.0000x reference)
//
#include <hip/hip_runtime.h>
#include <stdint.h>

#define Bdim 4
#define Sdim 2048
#define Ddim 512
#define Hdim 8
#define Mdim (Bdim*Sdim)   // 8192
#define Shalf 1024

typedef __attribute__((ext_vector_type(8))) short bf16x8;
typedef __attribute__((ext_vector_type(4))) float f32x4;
typedef __attribute__((ext_vector_type(4))) int i32x4;

#define SCALE 0.044194173824159216f   // 1/sqrt(512)
#define LOG2E 1.4426950408889634f

__device__ __forceinline__ unsigned short f2bf(float f){
  union { float f; unsigned int u; } v; v.f = f;
  unsigned int u = v.u + 0x7FFFu + ((v.u >> 16) & 1u);   // RNE
  return (unsigned short)(u >> 16);
}

__device__ __forceinline__ void gl_lds16(const void* g, void* l){
  __builtin_amdgcn_global_load_lds(
      (const __attribute__((address_space(1))) unsigned int*)g,
      (__attribute__((address_space(3))) unsigned int*)l, 16, 0, 0);
}

// parity permutation: row m (b*2048+s) -> b*2048 + (s&1)*1024 + (s>>1)
__device__ __forceinline__ int permrow(int m){
  return (m & ~2047) | ((m & 1) << 10) | ((m & 2047) >> 1);
}

// ---------------- prep: x fp32 -> bf16 ----------------
__global__ void cvt_x(const float* __restrict__ x, unsigned short* __restrict__ xb, int n8){
  int i = blockIdx.x*blockDim.x + threadIdx.x;
  if (i >= n8) return;
  const float4* p = (const float4*)x + (size_t)i*2;
  float4 a = p[0], b = p[1];
  union { unsigned short s[8]; i32x4 v; } o;
  o.s[0]=f2bf(a.x); o.s[1]=f2bf(a.y); o.s[2]=f2bf(a.z); o.s[3]=f2bf(a.w);
  o.s[4]=f2bf(b.x); o.s[5]=f2bf(b.y); o.s[6]=f2bf(b.z); o.s[7]=f2bf(b.w);
  ((i32x4*)xb)[i] = o.v;
}

// ---------------- prep: W fp32 [k][n] -> bf16 Wt [type*H+h][n][k] ----------------
__global__ void twk(const float* __restrict__ Wq, const float* __restrict__ Wk,
                    const float* __restrict__ Wv, unsigned short* __restrict__ Wt){
  __shared__ float t[32][33];
  int z = blockIdx.z;                       // type*H + h
  const float* W = (z < Hdim ? Wq : (z < 2*Hdim ? Wk : Wv)) + (size_t)(z % Hdim)*Ddim*Ddim;
  int n0 = blockIdx.x*32, k0 = blockIdx.y*32;
  #pragma unroll
  for (int i=0;i<4;i++){
    int k = k0 + threadIdx.y + i*8;
    t[threadIdx.y + i*8][threadIdx.x] = W[(size_t)k*Ddim + n0 + threadIdx.x];
  }
  __syncthreads();
  #pragma unroll
  for (int i=0;i<4;i++){
    int n = threadIdx.y + i*8;
    Wt[(size_t)z*Ddim*Ddim + (size_t)(n0+n)*Ddim + k0 + threadIdx.x] = f2bf(t[threadIdx.x][n]);
  }
}

// ---------------- projection: Q/K parity-permuted rows, V -> Vt [d][m'] ----------------
__launch_bounds__(256, 2)
__global__ void proj(const unsigned short* __restrict__ xb,
                     const unsigned short* __restrict__ Wt,
                     unsigned short* __restrict__ Qb,
                     unsigned short* __restrict__ Kb,
                     unsigned short* __restrict__ Vtb,
                     int h0, int g)
{
  __shared__ unsigned short smem[16640];    // A[0..4096) B[4096..8192) ; epilogue: [128][130]
  int tid = threadIdx.x, w = tid>>6, lane = tid&63;
  int wm = w>>1, wn = w&1;
  int y = blockIdx.y, g4 = 4*g;
  int type = y / g4; int rem = y - type*g4;
  int hrel = rem >> 2, nt = rem & 3;
  int m0 = blockIdx.x * 128, n0 = nt * 128;
  int l15 = lane&15, l4 = lane>>4;

  const unsigned short* Bsrc = Wt + (size_t)(type*Hdim + h0 + hrel)*Ddim*Ddim;

  f32x4 acc[4][4];
  #pragma unroll
  for (int i=0;i<4;i++)
    #pragma unroll
    for (int j=0;j<4;j++){ f32x4 z={0.f,0.f,0.f,0.f}; acc[i][j]=z; }

  for (int kt=0; kt<16; ++kt){
    int k0 = kt*32;
    #pragma unroll
    for (int i=0;i<2;i++){
      int row = i*64 + w*16 + (lane>>2);
      int cb  = lane&3;
      gl_lds16(xb   + (size_t)(m0+row)*Ddim + k0 + cb*8, (char*)smem + i*4096 + w*1024);
      gl_lds16(Bsrc + (size_t)(n0+row)*Ddim + k0 + cb*8, (char*)smem + 8192 + i*4096 + w*1024);
    }
    __syncthreads();
    bf16x8 af[4], bfr[4];
    #pragma unroll
    for (int i=0;i<4;i++){
      af[i]  = *(const bf16x8*)&smem[(wm*64 + i*16 + l15)*32 + l4*8];
      bfr[i] = *(const bf16x8*)&smem[4096 + (wn*64 + i*16 + l15)*32 + l4*8];
    }
    #pragma unroll
    for (int i=0;i<4;i++)
      #pragma unroll
      for (int j=0;j<4;j++)
        acc[i][j] = __builtin_amdgcn_mfma_f32_16x16x32_bf16(af[i], bfr[j], acc[i][j], 0,0,0);
    __syncthreads();
  }

  if (type < 2){
    unsigned short* Ob = (type==0 ? Qb : Kb) + (size_t)hrel*Mdim*Ddim;
    #pragma unroll
    for (int i=0;i<4;i++){
      int mb = m0 + wm*64 + i*16 + (l4<<2);
      #pragma unroll
      for (int j=0;j<4;j++){
        int col = n0 + wn*64 + j*16 + l15;
        #pragma unroll
        for (int r=0;r<4;r++)
          Ob[(size_t)permrow(mb + r)*Ddim + col] = f2bf(acc[i][j][r]);
      }
    }
  } else {
    // bounce-transpose tile through LDS, write Vt[d][m'] with parity-split columns
    #pragma unroll
    for (int i=0;i<4;i++){
      int ml = wm*64 + i*16 + (l4<<2);
      #pragma unroll
      for (int j=0;j<4;j++){
        int nl = wn*64 + j*16 + l15;
        #pragma unroll
        for (int r=0;r<4;r++)
          smem[(ml + r)*130 + nl] = f2bf(acc[i][j][r]);
      }
    }
    __syncthreads();
    unsigned short* Ovt = Vtb + (size_t)hrel*Ddim*Mdim;
    int bb  = m0 >> 11;
    int ib0 = (m0 & 2047) >> 1;     // i-base within parity block (64 i per tile)
    #pragma unroll
    for (int c=0;c<8;c++){
      int nl = c*16 + (tid>>4);     // d-local 0..127
      int il = (tid&15)*4;          // i-local 0..60 step 4
      #pragma unroll
      for (int pp=0; pp<2; pp++){
        union { unsigned short s[4]; uint2 v; } pk;
        #pragma unroll
        for (int ii=0;ii<4;ii++) pk.s[ii] = smem[(2*(il+ii)+pp)*130 + nl];
        *(uint2*)&Ovt[(size_t)(n0+nl)*Mdim + bb*Sdim + pp*Shalf + ib0 + il] = pk.v;
      }
    }
  }
}

// ---------------- staging (8 waves): K loads FIRST, then V loads ----------------
// Per wave: 4 K-loads then 4 V-loads (vmcnt counting relies on this order).
// dense: no clamps; spec: clamped (32-aligned tiles => clamped chunks fully masked).
__device__ __forceinline__ void stage_dense(const unsigned short* Kbase, int krow0,
                                            const unsigned short* Vblk, int vcol0,
                                            char* KsB, char* VsB, int w, int lane)
{
  int l15 = lane&15, l4 = lane>>4;
  #pragma unroll
  for (int jj=0;jj<4;jj++){
    int bi = w*4 + jj;
    int row = krow0 + ((bi>>4)<<4) + l15;
    int g   = ((bi&15)<<2) + l4;
    gl_lds16(Kbase + ((size_t)row<<9) + g*8, KsB + bi*1024);
  }
  #pragma unroll
  for (int jj=0;jj<4;jj++){
    int bi = w*4 + jj;
    int d   = (bi<<4) + l15;
    int col = vcol0 + l4*8;
    gl_lds16(Vblk + ((size_t)d<<13) + col, VsB + bi*1024);
  }
}
__device__ __forceinline__ void stage_spec(const unsigned short* Kbase, int krow0,
                                           const unsigned short* Vblk, int vcol0,
                                           char* KsB, char* VsB, int w, int lane)
{
  int l15 = lane&15, l4 = lane>>4;
  #pragma unroll
  for (int jj=0;jj<4;jj++){
    int bi = w*4 + jj;
    int row = krow0 + ((bi>>4)<<4) + l15;
    row = row < 0 ? 0 : (row > Shalf-1 ? Shalf-1 : row);
    int g   = ((bi&15)<<2) + l4;
    gl_lds16(Kbase + ((size_t)row<<9) + g*8, KsB + bi*1024);
  }
  #pragma unroll
  for (int jj=0;jj<4;jj++){
    int bi = w*4 + jj;
    int d   = (bi<<4) + l15;
    int col = vcol0 + l4*8;
    col = col < 0 ? 0 : (col > Shalf-8 ? Shalf-8 : col);
    gl_lds16(Vblk + ((size_t)d<<13) + col, VsB + bi*1024);
  }
}

// ---------------- flash attention, cross-tile pipelined (T15-analog) ----------------
// Per iteration: QK(t+1) issues first (K(t+1) already resident) and overlaps
// softmax(t)'s VALU chain + P-LDS round trip; then PV(t).  Stage order K-then-V
// makes vmcnt(4) complete exactly {V(t+1), K(t+2)} with V(t+2) still in flight.
#define NDENSE 32
#define NSPEC 5
#define NT (NDENSE + NSPEC)

__launch_bounds__(512, 2)
__global__ void attn(const unsigned short* __restrict__ Qb,
                     const unsigned short* __restrict__ Kb,
                     const unsigned short* __restrict__ Vtb,
                     float* __restrict__ out)
{
  __shared__ char lds[2*32768 + 2*32768 + 8*1024];   // Ks dbuf | Vs dbuf | Ps per-wave
  int tid = threadIdx.x, w = tid>>6, lane = tid&63;
  int l15 = lane&15, l4 = lane>>4;
  // grid = (z, qc): linear id = z + 64*qc -> XCD = z%8
  int z  = blockIdx.x;              // ((h*4+b)*2+p)
  int qc = blockIdx.y;              // 0..7 (128 queries each)
  int p  = z & 1; int zb = z >> 1; int b = zb & 3; int h = zb >> 2;

  const unsigned short* Qp     = Qb + (size_t)h*Mdim*Ddim + (size_t)(b*Sdim + p*Shalf)*Ddim;
  const unsigned short* Ksame  = Kb + (size_t)h*Mdim*Ddim + (size_t)(b*Sdim + p*Shalf)*Ddim;
  const unsigned short* Kopp   = Kb + (size_t)h*Mdim*Ddim + (size_t)(b*Sdim + (1-p)*Shalf)*Ddim;
  const unsigned short* Vt     = Vtb + (size_t)h*Ddim*Mdim;
  int csame = b*Sdim + p*Shalf;
  int copp  = b*Sdim + (1-p)*Shalf;
  int i0 = qc*128;
  int j0 = i0 - 32 + 32*p;          // parity-trimmed 32-aligned neighbor-window base

  // Q fragments in registers: rows i0 + w*16 + l15
  bf16x8 qa[16];
  {
    const unsigned short* qr = Qp + (size_t)(i0 + w*16 + l15)*Ddim;
    #pragma unroll
    for (int ks=0;ks<16;ks++) qa[ks] = *(const bf16x8*)&qr[ks*32 + l4*8];
  }

  f32x4 acc[32];
  #pragma unroll
  for (int n=0;n<32;n++){ f32x4 zz={0.f,0.f,0.f,0.f}; acc[n]=zz; }
  float ms[4], lp[4];
  #pragma unroll
  for (int r=0;r<4;r++){ ms[r] = -3.0e38f; lp[r] = 0.f; }

  // prologue: stage tiles 0 and 1 (both dense), wait K(0),V(0),K(1), compute S(0)
  stage_dense(Ksame, 0,  Vt + csame, 0,  lds,         lds + 65536,         w, lane);
  stage_dense(Ksame, 32, Vt + csame, 32, lds + 32768, lds + 65536 + 32768, w, lane);
  asm volatile("s_waitcnt vmcnt(4)" ::: "memory");   // 12 oldest = K0,V0,K1 landed; V1 in flight
  __builtin_amdgcn_s_barrier();
  __builtin_amdgcn_sched_barrier(0);

  f32x4 sc_prev[2];
  #pragma unroll
  for (int sub=0; sub<2; ++sub){
    f32x4 a0 = {0.f,0.f,0.f,0.f};
    #pragma unroll
    for (int ks=0;ks<16;ks++){
      bf16x8 kb = *(const bf16x8*)(lds + (sub*16+ks)*1024 + (l4*16+l15)*16);
      a0 = __builtin_amdgcn_mfma_f32_16x16x32_bf16(qa[ks], kb, a0, 0,0,0);
    }
    sc_prev[sub] = a0;
  }

  for (int t=0; t<NT; ++t){
    char* VsB = lds + 65536 + (t&1)*32768;

    // [A] QK(t+1) from the other buffer — overlaps SM(t) + P round trip below
    f32x4 sc_next[2];
    if (t + 1 < NT){
      char* KsN = lds + ((t+1)&1)*32768;
      #pragma unroll
      for (int sub=0; sub<2; ++sub){
        f32x4 a0 = {0.f,0.f,0.f,0.f};
        #pragma unroll
        for (int ks=0;ks<16;ks++){
          bf16x8 kb = *(const bf16x8*)(KsN + (sub*16+ks)*1024 + (l4*16+l15)*16);
          a0 = __builtin_amdgcn_mfma_f32_16x16x32_bf16(qa[ks], kb, a0, 0,0,0);
        }
        sc_next[sub] = a0;
      }
    }

    // [B] softmax(t) on sc_prev: defer-max, conditional cross-lane max, deferred row-sum
    float s0v[4], s1v[4], lmax[4];
    bool spec = (t >= NDENSE);
    int tbase = spec ? (j0 + (t-NDENSE)*32) : 0;
    #pragma unroll
    for (int r=0;r<4;r++){
      float s0 = sc_prev[0][r]*SCALE, s1 = sc_prev[1][r]*SCALE;
      if (spec){
        int iq = i0 + w*16 + l4*4 + r;
        int jA = tbase + l15;
        int jB = jA + 16;
        int tgt = iq - 1 + 2*p;
        bool vA = (jA>=0) & (jA<Shalf) & ((jA==iq) | (jA==tgt));
        bool vB = (jB>=0) & (jB<Shalf) & ((jB==iq) | (jB==tgt));
        if(!vA) s0 = -1e30f;
        if(!vB) s1 = -1e30f;
      }
      s0v[r]=s0; s1v[r]=s1;
      lmax[r] = fmaxf(s0, s1);
    }
    bool need = (lmax[0] > ms[0]+8.f) | (lmax[1] > ms[1]+8.f) |
                (lmax[2] > ms[2]+8.f) | (lmax[3] > ms[3]+8.f);
    if (__any(need)){
      #pragma unroll
      for (int r=0;r<4;r++){
        float tm = lmax[r];
        tm = fmaxf(tm, __shfl_xor(tm, 1));
        tm = fmaxf(tm, __shfl_xor(tm, 2));
        tm = fmaxf(tm, __shfl_xor(tm, 4));
        tm = fmaxf(tm, __shfl_xor(tm, 8));
        float nm = fmaxf(ms[r], tm);
        float rs = exp2f((ms[r]-nm)*LOG2E);
        ms[r] = nm; lp[r] *= rs;
        #pragma unroll
        for (int n=0;n<32;n++) acc[n][r] *= rs;
      }
    }

    // P = exp(s - m); per-lane partial row-sum; P to per-wave LDS (A-frag layout)
    char* PsB = lds + 131072 + w*1024;
    #pragma unroll
    for (int r=0;r<4;r++){
      float p0 = exp2f((s0v[r]-ms[r])*LOG2E);
      float p1 = exp2f((s1v[r]-ms[r])*LOG2E);
      lp[r] += p0 + p1;
      int q = l4*4 + r;
      *(unsigned short*)(PsB + (((l15>>3)*16 + q)*16 + (l15&7)*2))     = f2bf(p0);
      *(unsigned short*)(PsB + (((2+(l15>>3))*16 + q)*16 + (l15&7)*2)) = f2bf(p1);
    }
    asm volatile("s_waitcnt lgkmcnt(0)" ::: "memory");
    __builtin_amdgcn_sched_barrier(0);
    bf16x8 pa = *(const bf16x8*)(PsB + (l4*16+l15)*16);

    // PV(t): acc[n] over 32 d-fragments
    #pragma unroll
    for (int n=0;n<32;n++){
      bf16x8 vb = *(const bf16x8*)(VsB + n*1024 + (l4*16+l15)*16);
      acc[n] = __builtin_amdgcn_mfma_f32_16x16x32_bf16(pa, vb, acc[n], 0,0,0);
    }

    // end of tile t: all waves done reading K(t) (last iter) and V(t) (just now)
    __builtin_amdgcn_sched_barrier(0);
    __builtin_amdgcn_s_barrier();
    __builtin_amdgcn_sched_barrier(0);
    if (t + 2 < NT){
      int s = t + 2;
      char* KsS = lds + (s&1)*32768;
      char* VsS = lds + 65536 + (s&1)*32768;
      if (s < NDENSE)
        stage_dense(Ksame, s*32, Vt + csame, s*32, KsS, VsS, w, lane);
      else
        stage_spec(Kopp, j0 + (s-NDENSE)*32, Vt + copp, j0 + (s-NDENSE)*32, KsS, VsS, w, lane);
    }
    if (t + 1 < NT){
      if (t + 2 < NT){
        asm volatile("s_waitcnt vmcnt(4)" ::: "memory");  // completes V(t+1), K(t+2)
      } else {
        asm volatile("s_waitcnt vmcnt(0)" ::: "memory");  // tail: everything landed
      }
      __builtin_amdgcn_s_barrier();                       // publish across waves
      __builtin_amdgcn_sched_barrier(0);
      sc_prev[0] = sc_next[0];
      sc_prev[1] = sc_next[1];
    }
  }

  // epilogue: reduce row-sums once, normalize + head-mean via atomics
  #pragma unroll
  for (int r=0;r<4;r++){
    float t = lp[r];
    t += __shfl_xor(t, 1);
    t += __shfl_xor(t, 2);
    t += __shfl_xor(t, 4);
    t += __shfl_xor(t, 8);
    float inv = 0.125f / t;
    int i = i0 + w*16 + l4*4 + r;
    float* orow = out + (size_t)(b*Sdim + 2*i + p)*Ddim;
    #pragma unroll
    for (int n=0;n<32;n++)
      atomicAdd(&orow[n*16 + l15], acc[n][r]*inv);
  }
}

extern "C" void kernel_launch(void* const* d_in, const int* in_sizes, int n_in,
                              void* d_out, int out_size, void* d_ws, size_t ws_size,
                              hipStream_t stream)
{
  (void)in_sizes; (void)n_in;
  const float* x  = (const float*)d_in[0];
  const float* Wq = (const float*)d_in[1];
  const float* Wk = (const float*)d_in[2];
  const float* Wv = (const float*)d_in[3];
  float* out = (float*)d_out;

  const size_t xb_bytes = (size_t)Mdim*Ddim*2;        // 8 MB
  const size_t wt_bytes = (size_t)3*Hdim*Ddim*Ddim*2; // 12.6 MB
  const size_t per_head = (size_t)Mdim*Ddim*2;        // 8.4 MB

  int g = 8;
  while (g > 1 && xb_bytes + wt_bytes + 3*(size_t)g*per_head > ws_size) g >>= 1;

  unsigned short* xb  = (unsigned short*)d_ws;
  unsigned short* Wt  = (unsigned short*)((char*)d_ws + xb_bytes);
  unsigned short* Qb  = (unsigned short*)((char*)d_ws + xb_bytes + wt_bytes);
  unsigned short* Kb  = Qb + (size_t)g*Mdim*Ddim;
  unsigned short* Vtb = Kb + (size_t)g*Mdim*Ddim;

  hipMemsetAsync(d_out, 0, (size_t)out_size*sizeof(float), stream);
  cvt_x<<<dim3(Mdim*Ddim/8/256), dim3(256), 0, stream>>>(x, xb, Mdim*Ddim/8);
  twk<<<dim3(Ddim/32, Ddim/32, 3*Hdim), dim3(32,8), 0, stream>>>(Wq, Wk, Wv, Wt);

  for (int h0 = 0; h0 < Hdim; h0 += g){
    proj<<<dim3(Mdim/128, 12*g), dim3(256), 0, stream>>>(xb, Wt, Qb, Kb, Vtb, h0, g);
    attn<<<dim3(g*Bdim*2, Shalf/128 /*qc=8*/), dim3(512), 0, stream>>>(Qb, Kb, Vtb, out);
  }
}

// Round 12
// 589.143 us; speedup vs baseline: 1.0555x; 1.0555x over previous
//
#include <hip/hip_runtime.h>
#include <stdint.h>

#define Bdim 4
#define Sdim 2048
#define Ddim 512
#define Hdim 8
#define Mdim (Bdim*Sdim)   // 8192
#define Shalf 1024

typedef __attribute__((ext_vector_type(8))) short bf16x8;
typedef __attribute__((ext_vector_type(4))) float f32x4;
typedef __attribute__((ext_vector_type(4))) int i32x4;

#define SCALE 0.044194173824159216f   // 1/sqrt(512)
#define LOG2E 1.4426950408889634f

__device__ __forceinline__ unsigned short f2bf(float f){
  union { float f; unsigned int u; } v; v.f = f;
  unsigned int u = v.u + 0x7FFFu + ((v.u >> 16) & 1u);   // RNE
  return (unsigned short)(u >> 16);
}

__device__ __forceinline__ void gl_lds16(const void* g, void* l){
  __builtin_amdgcn_global_load_lds(
      (const __attribute__((address_space(1))) unsigned int*)g,
      (__attribute__((address_space(3))) unsigned int*)l, 16, 0, 0);
}

// parity permutation: row m (b*2048+s) -> b*2048 + (s&1)*1024 + (s>>1)
__device__ __forceinline__ int permrow(int m){
  return (m & ~2047) | ((m & 1) << 10) | ((m & 2047) >> 1);
}

// ---------------- prep: x fp32 -> bf16 ----------------
__global__ void cvt_x(const float* __restrict__ x, unsigned short* __restrict__ xb, int n8){
  int i = blockIdx.x*blockDim.x + threadIdx.x;
  if (i >= n8) return;
  const float4* p = (const float4*)x + (size_t)i*2;
  float4 a = p[0], b = p[1];
  union { unsigned short s[8]; i32x4 v; } o;
  o.s[0]=f2bf(a.x); o.s[1]=f2bf(a.y); o.s[2]=f2bf(a.z); o.s[3]=f2bf(a.w);
  o.s[4]=f2bf(b.x); o.s[5]=f2bf(b.y); o.s[6]=f2bf(b.z); o.s[7]=f2bf(b.w);
  ((i32x4*)xb)[i] = o.v;
}

// ---------------- prep: W fp32 [k][n] -> bf16 Wt [type*H+h][n][k] ----------------
__global__ void twk(const float* __restrict__ Wq, const float* __restrict__ Wk,
                    const float* __restrict__ Wv, unsigned short* __restrict__ Wt){
  __shared__ float t[32][33];
  int z = blockIdx.z;                       // type*H + h
  const float* W = (z < Hdim ? Wq : (z < 2*Hdim ? Wk : Wv)) + (size_t)(z % Hdim)*Ddim*Ddim;
  int n0 = blockIdx.x*32, k0 = blockIdx.y*32;
  #pragma unroll
  for (int i=0;i<4;i++){
    int k = k0 + threadIdx.y + i*8;
    t[threadIdx.y + i*8][threadIdx.x] = W[(size_t)k*Ddim + n0 + threadIdx.x];
  }
  __syncthreads();
  #pragma unroll
  for (int i=0;i<4;i++){
    int n = threadIdx.y + i*8;
    Wt[(size_t)z*Ddim*Ddim + (size_t)(n0+n)*Ddim + k0 + threadIdx.x] = f2bf(t[threadIdx.x][n]);
  }
}

// ---------------- projection: Q/K parity-permuted rows, V -> Vt [d][m'] ----------------
__launch_bounds__(256, 2)
__global__ void proj(const unsigned short* __restrict__ xb,
                     const unsigned short* __restrict__ Wt,
                     unsigned short* __restrict__ Qb,
                     unsigned short* __restrict__ Kb,
                     unsigned short* __restrict__ Vtb,
                     int h0, int g)
{
  __shared__ unsigned short smem[16640];    // A[0..4096) B[4096..8192) ; epilogue: [128][130]
  int tid = threadIdx.x, w = tid>>6, lane = tid&63;
  int wm = w>>1, wn = w&1;
  int y = blockIdx.y, g4 = 4*g;
  int type = y / g4; int rem = y - type*g4;
  int hrel = rem >> 2, nt = rem & 3;
  int m0 = blockIdx.x * 128, n0 = nt * 128;
  int l15 = lane&15, l4 = lane>>4;

  const unsigned short* Bsrc = Wt + (size_t)(type*Hdim + h0 + hrel)*Ddim*Ddim;

  f32x4 acc[4][4];
  #pragma unroll
  for (int i=0;i<4;i++)
    #pragma unroll
    for (int j=0;j<4;j++){ f32x4 z={0.f,0.f,0.f,0.f}; acc[i][j]=z; }

  for (int kt=0; kt<16; ++kt){
    int k0 = kt*32;
    #pragma unroll
    for (int i=0;i<2;i++){
      int row = i*64 + w*16 + (lane>>2);
      int cb  = lane&3;
      gl_lds16(xb   + (size_t)(m0+row)*Ddim + k0 + cb*8, (char*)smem + i*4096 + w*1024);
      gl_lds16(Bsrc + (size_t)(n0+row)*Ddim + k0 + cb*8, (char*)smem + 8192 + i*4096 + w*1024);
    }
    __syncthreads();
    bf16x8 af[4], bfr[4];
    #pragma unroll
    for (int i=0;i<4;i++){
      af[i]  = *(const bf16x8*)&smem[(wm*64 + i*16 + l15)*32 + l4*8];
      bfr[i] = *(const bf16x8*)&smem[4096 + (wn*64 + i*16 + l15)*32 + l4*8];
    }
    #pragma unroll
    for (int i=0;i<4;i++)
      #pragma unroll
      for (int j=0;j<4;j++)
        acc[i][j] = __builtin_amdgcn_mfma_f32_16x16x32_bf16(af[i], bfr[j], acc[i][j], 0,0,0);
    __syncthreads();
  }

  if (type < 2){
    unsigned short* Ob = (type==0 ? Qb : Kb) + (size_t)hrel*Mdim*Ddim;
    #pragma unroll
    for (int i=0;i<4;i++){
      int mb = m0 + wm*64 + i*16 + (l4<<2);
      #pragma unroll
      for (int j=0;j<4;j++){
        int col = n0 + wn*64 + j*16 + l15;
        #pragma unroll
        for (int r=0;r<4;r++)
          Ob[(size_t)permrow(mb + r)*Ddim + col] = f2bf(acc[i][j][r]);
      }
    }
  } else {
    // bounce-transpose tile through LDS, write Vt[d][m'] with parity-split columns
    #pragma unroll
    for (int i=0;i<4;i++){
      int ml = wm*64 + i*16 + (l4<<2);
      #pragma unroll
      for (int j=0;j<4;j++){
        int nl = wn*64 + j*16 + l15;
        #pragma unroll
        for (int r=0;r<4;r++)
          smem[(ml + r)*130 + nl] = f2bf(acc[i][j][r]);
      }
    }
    __syncthreads();
    unsigned short* Ovt = Vtb + (size_t)hrel*Ddim*Mdim;
    int bb  = m0 >> 11;
    int ib0 = (m0 & 2047) >> 1;     // i-base within parity block (64 i per tile)
    #pragma unroll
    for (int c=0;c<8;c++){
      int nl = c*16 + (tid>>4);     // d-local 0..127
      int il = (tid&15)*4;          // i-local 0..60 step 4
      #pragma unroll
      for (int pp=0; pp<2; pp++){
        union { unsigned short s[4]; uint2 v; } pk;
        #pragma unroll
        for (int ii=0;ii<4;ii++) pk.s[ii] = smem[(2*(il+ii)+pp)*130 + nl];
        *(uint2*)&Ovt[(size_t)(n0+nl)*Mdim + bb*Sdim + pp*Shalf + ib0 + il] = pk.v;
      }
    }
  }
}

// ---------------- staging (8 waves, bi = w*4+jj, 8 loads/wave) ----------------
__device__ __forceinline__ void stage_dense(const unsigned short* Kbase, int krow0,
                                            const unsigned short* Vblk, int vcol0,
                                            char* KsB, char* VsB, int w, int lane)
{
  int l15 = lane&15, l4 = lane>>4;
  #pragma unroll
  for (int jj=0;jj<4;jj++){
    int bi = w*4 + jj;
    int row = krow0 + ((bi>>4)<<4) + l15;
    int g   = ((bi&15)<<2) + l4;
    gl_lds16(Kbase + ((size_t)row<<9) + g*8, KsB + bi*1024);
    int d   = (bi<<4) + l15;
    int col = vcol0 + l4*8;
    gl_lds16(Vblk + ((size_t)d<<13) + col, VsB + bi*1024);
  }
}
__device__ __forceinline__ void stage_spec(const unsigned short* Kbase, int krow0,
                                           const unsigned short* Vblk, int vcol0,
                                           char* KsB, char* VsB, int w, int lane)
{
  int l15 = lane&15, l4 = lane>>4;
  #pragma unroll
  for (int jj=0;jj<4;jj++){
    int bi = w*4 + jj;
    int row = krow0 + ((bi>>4)<<4) + l15;
    row = row < 0 ? 0 : (row > Shalf-1 ? Shalf-1 : row);
    int g   = ((bi&15)<<2) + l4;
    gl_lds16(Kbase + ((size_t)row<<9) + g*8, KsB + bi*1024);
    int d   = (bi<<4) + l15;
    int col = vcol0 + l4*8;
    col = col < 0 ? 0 : (col > Shalf-8 ? Shalf-8 : col);
    gl_lds16(Vblk + ((size_t)d<<13) + col, VsB + bi*1024);
  }
}

// ---------------- flash attention over parity-dense sequences ----------------
// R7 structure + T19 sched_group_barrier chains forcing {4x DS_READ -> 4x MFMA}
// emission interleave in QK and PV (4-deep read batching without extra VGPRs).
#define NDENSE 32
#define NSPEC 5
#define NT (NDENSE + NSPEC)

__launch_bounds__(512, 2)
__global__ void attn(const unsigned short* __restrict__ Qb,
                     const unsigned short* __restrict__ Kb,
                     const unsigned short* __restrict__ Vtb,
                     float* __restrict__ out)
{
  __shared__ char lds[2*32768 + 2*32768 + 8*1024];   // Ks dbuf | Vs dbuf | Ps per-wave
  int tid = threadIdx.x, w = tid>>6, lane = tid&63;
  int l15 = lane&15, l4 = lane>>4;
  // grid = (z, qc): linear id = z + 64*qc -> XCD = z%8
  int z  = blockIdx.x;              // ((h*4+b)*2+p)
  int qc = blockIdx.y;              // 0..7 (128 queries each)
  int p  = z & 1; int zb = z >> 1; int b = zb & 3; int h = zb >> 2;

  const unsigned short* Qp     = Qb + (size_t)h*Mdim*Ddim + (size_t)(b*Sdim + p*Shalf)*Ddim;
  const unsigned short* Ksame  = Kb + (size_t)h*Mdim*Ddim + (size_t)(b*Sdim + p*Shalf)*Ddim;
  const unsigned short* Kopp   = Kb + (size_t)h*Mdim*Ddim + (size_t)(b*Sdim + (1-p)*Shalf)*Ddim;
  const unsigned short* Vt     = Vtb + (size_t)h*Ddim*Mdim;
  int csame = b*Sdim + p*Shalf;
  int copp  = b*Sdim + (1-p)*Shalf;
  int i0 = qc*128;
  int j0 = i0 - 32 + 32*p;          // parity-trimmed 32-aligned neighbor-window base

  // Q fragments in registers: rows i0 + w*16 + l15
  bf16x8 qa[16];
  {
    const unsigned short* qr = Qp + (size_t)(i0 + w*16 + l15)*Ddim;
    #pragma unroll
    for (int ks=0;ks<16;ks++) qa[ks] = *(const bf16x8*)&qr[ks*32 + l4*8];
  }

  f32x4 acc[32];
  #pragma unroll
  for (int n=0;n<32;n++){ f32x4 zz={0.f,0.f,0.f,0.f}; acc[n]=zz; }
  float ms[4], lp[4];
  #pragma unroll
  for (int r=0;r<4;r++){ ms[r] = -3.0e38f; lp[r] = 0.f; }

  // prologue: stage tile 0 (dense, fully in-range)
  stage_dense(Ksame, 0, Vt + csame, 0, lds, lds + 65536, w, lane);

  for (int t=0; t<NT; ++t){
    int buf = t & 1;
    char* KsB = lds + buf*32768;
    char* VsB = lds + 65536 + buf*32768;

    __builtin_amdgcn_sched_barrier(0);
    __builtin_amdgcn_s_barrier();            // all waves done reading buf^1 (tile t-1)
    if (t + 1 < NT){
      char* KsN = lds + (buf^1)*32768;
      char* VsN = lds + 65536 + (buf^1)*32768;
      if (t + 1 < NDENSE)
        stage_dense(Ksame, (t+1)*32, Vt + csame, (t+1)*32, KsN, VsN, w, lane);
      else {
        int tt = t + 1 - NDENSE;
        stage_spec(Kopp, j0 + tt*32, Vt + copp, j0 + tt*32, KsN, VsN, w, lane);
      }
      asm volatile("s_waitcnt vmcnt(8)" ::: "memory");   // tile t's 8 loads done; t+1 in flight
    } else {
      asm volatile("s_waitcnt vmcnt(0)" ::: "memory");
    }
    __builtin_amdgcn_s_barrier();            // publish tile t across waves
    __builtin_amdgcn_sched_barrier(0);

    // QK^T : S[16 q][32 keys] per wave (even/odd accumulator chains)
    f32x4 sc[2];
    #pragma unroll
    for (int sub=0; sub<2; ++sub){
      f32x4 ae = {0.f,0.f,0.f,0.f}, ao = {0.f,0.f,0.f,0.f};
      #pragma unroll
      for (int ks=0;ks<16;ks+=2){
        bf16x8 k0 = *(const bf16x8*)(KsB + (sub*16+ks)*1024   + (l4*16+l15)*16);
        bf16x8 k1 = *(const bf16x8*)(KsB + (sub*16+ks+1)*1024 + (l4*16+l15)*16);
        ae = __builtin_amdgcn_mfma_f32_16x16x32_bf16(qa[ks],   k0, ae, 0,0,0);
        ao = __builtin_amdgcn_mfma_f32_16x16x32_bf16(qa[ks+1], k1, ao, 0,0,0);
      }
      sc[sub] = ae + ao;
    }
    // T19: force {4x ds_read -> 4x mfma} interleave (4-deep read batching)
    #pragma unroll
    for (int gq=0; gq<8; ++gq){
      __builtin_amdgcn_sched_group_barrier(0x100, 4, 0);  // DS_READ x4
      __builtin_amdgcn_sched_group_barrier(0x008, 4, 0);  // MFMA x4
    }

    // softmax: defer-max; cross-lane max only when triggered; row-sum deferred
    float s0v[4], s1v[4], lmax[4];
    bool spec = (t >= NDENSE);
    int tbase = spec ? (j0 + (t-NDENSE)*32) : 0;
    #pragma unroll
    for (int r=0;r<4;r++){
      float s0 = sc[0][r]*SCALE, s1 = sc[1][r]*SCALE;
      if (spec){
        int iq = i0 + w*16 + l4*4 + r;
        int jA = tbase + l15;
        int jB = jA + 16;
        int tgt = iq - 1 + 2*p;
        bool vA = (jA>=0) & (jA<Shalf) & ((jA==iq) | (jA==tgt));
        bool vB = (jB>=0) & (jB<Shalf) & ((jB==iq) | (jB==tgt));
        if(!vA) s0 = -1e30f;
        if(!vB) s1 = -1e30f;
      }
      s0v[r]=s0; s1v[r]=s1;
      lmax[r] = fmaxf(s0, s1);
    }
    bool need = (lmax[0] > ms[0]+8.f) | (lmax[1] > ms[1]+8.f) |
                (lmax[2] > ms[2]+8.f) | (lmax[3] > ms[3]+8.f);
    if (__any(need)){
      #pragma unroll
      for (int r=0;r<4;r++){
        float tm = lmax[r];
        tm = fmaxf(tm, __shfl_xor(tm, 1));
        tm = fmaxf(tm, __shfl_xor(tm, 2));
        tm = fmaxf(tm, __shfl_xor(tm, 4));
        tm = fmaxf(tm, __shfl_xor(tm, 8));
        float nm = fmaxf(ms[r], tm);
        float rs = exp2f((ms[r]-nm)*LOG2E);
        ms[r] = nm; lp[r] *= rs;
        #pragma unroll
        for (int n=0;n<32;n++) acc[n][r] *= rs;
      }
    }

    // P = exp(s - m); per-lane partial row-sum; P to per-wave LDS (A-frag layout)
    char* PsB = lds + 131072 + w*1024;
    #pragma unroll
    for (int r=0;r<4;r++){
      float p0 = exp2f((s0v[r]-ms[r])*LOG2E);
      float p1 = exp2f((s1v[r]-ms[r])*LOG2E);
      lp[r] += p0 + p1;
      int q = l4*4 + r;
      *(unsigned short*)(PsB + (((l15>>3)*16 + q)*16 + (l15&7)*2))     = f2bf(p0);
      *(unsigned short*)(PsB + (((2+(l15>>3))*16 + q)*16 + (l15&7)*2)) = f2bf(p1);
    }
    asm volatile("s_waitcnt lgkmcnt(0)" ::: "memory");
    __builtin_amdgcn_sched_barrier(0);
    bf16x8 pa = *(const bf16x8*)(PsB + (l4*16+l15)*16);

    // PV: acc[n] over 32 d-fragments
    #pragma unroll
    for (int n=0;n<32;n++){
      bf16x8 vb = *(const bf16x8*)(VsB + n*1024 + (l4*16+l15)*16);
      acc[n] = __builtin_amdgcn_mfma_f32_16x16x32_bf16(pa, vb, acc[n], 0,0,0);
    }
    // T19: pa read first, then {4x ds_read -> 4x mfma} batches
    __builtin_amdgcn_sched_group_barrier(0x100, 1, 0);    // pa
    #pragma unroll
    for (int gp=0; gp<8; ++gp){
      __builtin_amdgcn_sched_group_barrier(0x100, 4, 0);  // DS_READ x4
      __builtin_amdgcn_sched_group_barrier(0x008, 4, 0);  // MFMA x4
    }
  }

  // epilogue: reduce row-sums once, normalize + head-mean via atomics
  #pragma unroll
  for (int r=0;r<4;r++){
    float t = lp[r];
    t += __shfl_xor(t, 1);
    t += __shfl_xor(t, 2);
    t += __shfl_xor(t, 4);
    t += __shfl_xor(t, 8);
    float inv = 0.125f / t;
    int i = i0 + w*16 + l4*4 + r;
    float* orow = out + (size_t)(b*Sdim + 2*i + p)*Ddim;
    #pragma unroll
    for (int n=0;n<32;n++)
      atomicAdd(&orow[n*16 + l15], acc[n][r]*inv);
  }
}

extern "C" void kernel_launch(void* const* d_in, const int* in_sizes, int n_in,
                              void* d_out, int out_size, void* d_ws, size_t ws_size,
                              hipStream_t stream)
{
  (void)in_sizes; (void)n_in;
  const float* x  = (const float*)d_in[0];
  const float* Wq = (const float*)d_in[1];
  const float* Wk = (const float*)d_in[2];
  const float* Wv = (const float*)d_in[3];
  float* out = (float*)d_out;

  const size_t xb_bytes = (size_t)Mdim*Ddim*2;        // 8 MB
  const size_t wt_bytes = (size_t)3*Hdim*Ddim*Ddim*2; // 12.6 MB
  const size_t per_head = (size_t)Mdim*Ddim*2;        // 8.4 MB

  int g = 8;
  while (g > 1 && xb_bytes + wt_bytes + 3*(size_t)g*per_head > ws_size) g >>= 1;

  unsigned short* xb  = (unsigned short*)d_ws;
  unsigned short* Wt  = (unsigned short*)((char*)d_ws + xb_bytes);
  unsigned short* Qb  = (unsigned short*)((char*)d_ws + xb_bytes + wt_bytes);
  unsigned short* Kb  = Qb + (size_t)g*Mdim*Ddim;
  unsigned short* Vtb = Kb + (size_t)g*Mdim*Ddim;

  hipMemsetAsync(d_out, 0, (size_t)out_size*sizeof(float), stream);
  cvt_x<<<dim3(Mdim*Ddim/8/256), dim3(256), 0, stream>>>(x, xb, Mdim*Ddim/8);
  twk<<<dim3(Ddim/32, Ddim/32, 3*Hdim), dim3(32,8), 0, stream>>>(Wq, Wk, Wv, Wt);

  for (int h0 = 0; h0 < Hdim; h0 += g){
    proj<<<dim3(Mdim/128, 12*g), dim3(256), 0, stream>>>(xb, Wt, Qb, Kb, Vtb, h0, g);
    attn<<<dim3(g*Bdim*2, Shalf/128 /*qc=8*/), dim3(512), 0, stream>>>(Qb, Kb, Vtb, out);
  }
}

// Round 13
// 561.035 us; speedup vs baseline: 1.1083x; 1.0501x over previous
//
#include <hip/hip_runtime.h>
#include <stdint.h>

#define Bdim 4
#define Sdim 2048
#define Ddim 512
#define Hdim 8
#define Mdim (Bdim*Sdim)   // 8192
#define Shalf 1024

typedef __attribute__((ext_vector_type(8))) short bf16x8;
typedef __attribute__((ext_vector_type(4))) float f32x4;
typedef __attribute__((ext_vector_type(16))) float f32x16;
typedef __attribute__((ext_vector_type(4))) int i32x4;

#define SCALE 0.044194173824159216f   // 1/sqrt(512)
#define LOG2E 1.4426950408889634f

__device__ __forceinline__ unsigned short f2bf(float f){
  union { float f; unsigned int u; } v; v.f = f;
  unsigned int u = v.u + 0x7FFFu + ((v.u >> 16) & 1u);   // RNE
  return (unsigned short)(u >> 16);
}

__device__ __forceinline__ void gl_lds16(const void* g, void* l){
  __builtin_amdgcn_global_load_lds(
      (const __attribute__((address_space(1))) unsigned int*)g,
      (__attribute__((address_space(3))) unsigned int*)l, 16, 0, 0);
}

// parity permutation: row m (b*2048+s) -> b*2048 + (s&1)*1024 + (s>>1)
__device__ __forceinline__ int permrow(int m){
  return (m & ~2047) | ((m & 1) << 10) | ((m & 2047) >> 1);
}

// ---------------- prep: x fp32 -> bf16 ----------------
__global__ void cvt_x(const float* __restrict__ x, unsigned short* __restrict__ xb, int n8){
  int i = blockIdx.x*blockDim.x + threadIdx.x;
  if (i >= n8) return;
  const float4* p = (const float4*)x + (size_t)i*2;
  float4 a = p[0], b = p[1];
  union { unsigned short s[8]; i32x4 v; } o;
  o.s[0]=f2bf(a.x); o.s[1]=f2bf(a.y); o.s[2]=f2bf(a.z); o.s[3]=f2bf(a.w);
  o.s[4]=f2bf(b.x); o.s[5]=f2bf(b.y); o.s[6]=f2bf(b.z); o.s[7]=f2bf(b.w);
  ((i32x4*)xb)[i] = o.v;
}

// ---------------- prep: W fp32 [k][n] -> bf16 Wt [type*H+h][n][k] ----------------
__global__ void twk(const float* __restrict__ Wq, const float* __restrict__ Wk,
                    const float* __restrict__ Wv, unsigned short* __restrict__ Wt){
  __shared__ float t[32][33];
  int z = blockIdx.z;                       // type*H + h
  const float* W = (z < Hdim ? Wq : (z < 2*Hdim ? Wk : Wv)) + (size_t)(z % Hdim)*Ddim*Ddim;
  int n0 = blockIdx.x*32, k0 = blockIdx.y*32;
  #pragma unroll
  for (int i=0;i<4;i++){
    int k = k0 + threadIdx.y + i*8;
    t[threadIdx.y + i*8][threadIdx.x] = W[(size_t)k*Ddim + n0 + threadIdx.x];
  }
  __syncthreads();
  #pragma unroll
  for (int i=0;i<4;i++){
    int n = threadIdx.y + i*8;
    Wt[(size_t)z*Ddim*Ddim + (size_t)(n0+n)*Ddim + k0 + threadIdx.x] = f2bf(t[threadIdx.x][n]);
  }
}

// ---------------- projection: Q/K parity-permuted rows, V -> Vt [d][m'] ----------------
__launch_bounds__(256, 2)
__global__ void proj(const unsigned short* __restrict__ xb,
                     const unsigned short* __restrict__ Wt,
                     unsigned short* __restrict__ Qb,
                     unsigned short* __restrict__ Kb,
                     unsigned short* __restrict__ Vtb,
                     int h0, int g)
{
  __shared__ unsigned short smem[16640];    // A[0..4096) B[4096..8192) ; epilogue: [128][130]
  int tid = threadIdx.x, w = tid>>6, lane = tid&63;
  int wm = w>>1, wn = w&1;
  int y = blockIdx.y, g4 = 4*g;
  int type = y / g4; int rem = y - type*g4;
  int hrel = rem >> 2, nt = rem & 3;
  int m0 = blockIdx.x * 128, n0 = nt * 128;
  int l15 = lane&15, l4 = lane>>4;

  const unsigned short* Bsrc = Wt + (size_t)(type*Hdim + h0 + hrel)*Ddim*Ddim;

  f32x4 acc[4][4];
  #pragma unroll
  for (int i=0;i<4;i++)
    #pragma unroll
    for (int j=0;j<4;j++){ f32x4 z={0.f,0.f,0.f,0.f}; acc[i][j]=z; }

  for (int kt=0; kt<16; ++kt){
    int k0 = kt*32;
    #pragma unroll
    for (int i=0;i<2;i++){
      int row = i*64 + w*16 + (lane>>2);
      int cb  = lane&3;
      gl_lds16(xb   + (size_t)(m0+row)*Ddim + k0 + cb*8, (char*)smem + i*4096 + w*1024);
      gl_lds16(Bsrc + (size_t)(n0+row)*Ddim + k0 + cb*8, (char*)smem + 8192 + i*4096 + w*1024);
    }
    __syncthreads();
    bf16x8 af[4], bfr[4];
    #pragma unroll
    for (int i=0;i<4;i++){
      af[i]  = *(const bf16x8*)&smem[(wm*64 + i*16 + l15)*32 + l4*8];
      bfr[i] = *(const bf16x8*)&smem[4096 + (wn*64 + i*16 + l15)*32 + l4*8];
    }
    #pragma unroll
    for (int i=0;i<4;i++)
      #pragma unroll
      for (int j=0;j<4;j++)
        acc[i][j] = __builtin_amdgcn_mfma_f32_16x16x32_bf16(af[i], bfr[j], acc[i][j], 0,0,0);
    __syncthreads();
  }

  if (type < 2){
    unsigned short* Ob = (type==0 ? Qb : Kb) + (size_t)hrel*Mdim*Ddim;
    #pragma unroll
    for (int i=0;i<4;i++){
      int mb = m0 + wm*64 + i*16 + (l4<<2);
      #pragma unroll
      for (int j=0;j<4;j++){
        int col = n0 + wn*64 + j*16 + l15;
        #pragma unroll
        for (int r=0;r<4;r++)
          Ob[(size_t)permrow(mb + r)*Ddim + col] = f2bf(acc[i][j][r]);
      }
    }
  } else {
    // bounce-transpose tile through LDS, write Vt[d][m'] with parity-split columns
    #pragma unroll
    for (int i=0;i<4;i++){
      int ml = wm*64 + i*16 + (l4<<2);
      #pragma unroll
      for (int j=0;j<4;j++){
        int nl = wn*64 + j*16 + l15;
        #pragma unroll
        for (int r=0;r<4;r++)
          smem[(ml + r)*130 + nl] = f2bf(acc[i][j][r]);
      }
    }
    __syncthreads();
    unsigned short* Ovt = Vtb + (size_t)hrel*Ddim*Mdim;
    int bb  = m0 >> 11;
    int ib0 = (m0 & 2047) >> 1;     // i-base within parity block (64 i per tile)
    #pragma unroll
    for (int c=0;c<8;c++){
      int nl = c*16 + (tid>>4);     // d-local 0..127
      int il = (tid&15)*4;          // i-local 0..60 step 4
      #pragma unroll
      for (int pp=0; pp<2; pp++){
        union { unsigned short s[4]; uint2 v; } pk;
        #pragma unroll
        for (int ii=0;ii<4;ii++) pk.s[ii] = smem[(2*(il+ii)+pp)*130 + nl];
        *(uint2*)&Ovt[(size_t)(n0+nl)*Mdim + bb*Sdim + pp*Shalf + ib0 + il] = pk.v;
      }
    }
  }
}

// ---------------- staging (8 waves, bi = w*4+jj, 8 loads/wave) ----------------
__device__ __forceinline__ void stage_dense(const unsigned short* Kbase, int krow0,
                                            const unsigned short* Vblk, int vcol0,
                                            char* KsB, char* VsB, int w, int lane)
{
  int l15 = lane&15, l4 = lane>>4;
  #pragma unroll
  for (int jj=0;jj<4;jj++){
    int bi = w*4 + jj;
    int row = krow0 + ((bi>>4)<<4) + l15;
    int g   = ((bi&15)<<2) + l4;
    gl_lds16(Kbase + ((size_t)row<<9) + g*8, KsB + bi*1024);
    int d   = (bi<<4) + l15;
    int col = vcol0 + l4*8;
    gl_lds16(Vblk + ((size_t)d<<13) + col, VsB + bi*1024);
  }
}
__device__ __forceinline__ void stage_spec(const unsigned short* Kbase, int krow0,
                                           const unsigned short* Vblk, int vcol0,
                                           char* KsB, char* VsB, int w, int lane)
{
  int l15 = lane&15, l4 = lane>>4;
  #pragma unroll
  for (int jj=0;jj<4;jj++){
    int bi = w*4 + jj;
    int row = krow0 + ((bi>>4)<<4) + l15;
    row = row < 0 ? 0 : (row > Shalf-1 ? Shalf-1 : row);
    int g   = ((bi&15)<<2) + l4;
    gl_lds16(Kbase + ((size_t)row<<9) + g*8, KsB + bi*1024);
    int d   = (bi<<4) + l15;
    int col = vcol0 + l4*8;
    col = col < 0 ? 0 : (col > Shalf-8 ? Shalf-8 : col);
    gl_lds16(Vblk + ((size_t)d<<13) + col, VsB + bi*1024);
  }
}

// ---------------- flash attention: 32x32 swapped-QK^T, d-split waves -------------
// 8 waves = 4 q-groups (32q) x 2 d-halves (256d).  QK: mfma(K,Q) -> S[key][q],
// partial over own d-half, summed with partner via LDS exchange.  Softmax fully
// per-lane (lane owns q = lane&31, 16 of 32 keys in regs; fixed reference max).
// P -> A-frags via v_cvt_pk_bf16_f32 + v_permlane32_swap_b32 (no LDS round trip).
#define NDENSE 32
#define NSPEC 5
#define NT (NDENSE + NSPEC)

__launch_bounds__(512, 2)
__global__ void attn(const unsigned short* __restrict__ Qb,
                     const unsigned short* __restrict__ Kb,
                     const unsigned short* __restrict__ Vtb,
                     float* __restrict__ out)
{
  __shared__ char lds[163840];   // Ks dbuf 64K | Vs dbuf 64K | Xch 32K
  int tid = threadIdx.x, w = tid>>6, lane = tid&63;
  int qg = w>>1, dg = w&1;
  int ql = lane&31, hh = lane>>5;
  // grid = (z, qc): linear id = z + 64*qc -> XCD = z%8
  int z  = blockIdx.x;              // ((h*4+b)*2+p)
  int qc = blockIdx.y;              // 0..7 (128 queries each)
  int p  = z & 1; int zb = z >> 1; int b = zb & 3; int hd = zb >> 2;

  const unsigned short* Qp    = Qb + (size_t)hd*Mdim*Ddim + (size_t)(b*Sdim + p*Shalf)*Ddim;
  const unsigned short* Ksame = Kb + (size_t)hd*Mdim*Ddim + (size_t)(b*Sdim + p*Shalf)*Ddim;
  const unsigned short* Kopp  = Kb + (size_t)hd*Mdim*Ddim + (size_t)(b*Sdim + (1-p)*Shalf)*Ddim;
  const unsigned short* Vt    = Vtb + (size_t)hd*Ddim*Mdim;
  int csame = b*Sdim + p*Shalf;
  int copp  = b*Sdim + (1-p)*Shalf;
  int i0 = qc*128;
  int j0 = i0 - 32 + 32*p;          // parity-trimmed 32-aligned neighbor-window base

  const float C1 = SCALE*LOG2E;
  const float C0 = -4.0f*LOG2E;     // fixed softmax reference M=4 (scores*SCALE <~ 1.6)

  // Q fragments (B operand): rows q = i0+qg*32+ql, d = dg*256 + st*16 + hh*8 + j
  bf16x8 qf[16];
  {
    const unsigned short* qr = Qp + (size_t)(i0 + qg*32 + ql)*Ddim + dg*256 + hh*8;
    #pragma unroll
    for (int st=0; st<16; ++st) qf[st] = *(const bf16x8*)(qr + st*16);
  }

  f32x16 acc[8];
  #pragma unroll
  for (int dt=0; dt<8; ++dt)
    #pragma unroll
    for (int j=0; j<16; ++j) acc[dt][j] = 0.f;
  float lp = 0.f;

  char* Xch = lds + 131072;
  int iq  = i0 + qg*32 + ql;
  int tgt = iq - 1 + 2*p;

  // prologue: stage tile 0 (dense)
  stage_dense(Ksame, 0, Vt + csame, 0, lds, lds + 65536, w, lane);

  for (int t=0; t<NT; ++t){
    int buf = t & 1;
    char* KsB = lds + buf*32768;
    char* VsB = lds + 65536 + buf*32768;

    __builtin_amdgcn_sched_barrier(0);
    __builtin_amdgcn_s_barrier();            // B1: buf^1 free, Xch(t-1) consumed
    if (t + 1 < NT){
      char* KsN = lds + (buf^1)*32768;
      char* VsN = lds + 65536 + (buf^1)*32768;
      if (t + 1 < NDENSE)
        stage_dense(Ksame, (t+1)*32, Vt + csame, (t+1)*32, KsN, VsN, w, lane);
      else {
        int tt = t + 1 - NDENSE;
        stage_spec(Kopp, j0 + tt*32, Vt + copp, j0 + tt*32, KsN, VsN, w, lane);
      }
      asm volatile("s_waitcnt vmcnt(8)" ::: "memory");   // tile t's 8 loads done
    } else {
      asm volatile("s_waitcnt vmcnt(0)" ::: "memory");
    }
    __builtin_amdgcn_s_barrier();            // B2: tile t published
    __builtin_amdgcn_sched_barrier(0);

    // QK^T partial over this wave's 256 d:  S[key][q] = K · Q^T
    f32x16 sc;
    #pragma unroll
    for (int j=0; j<16; ++j) sc[j] = 0.f;
    #pragma unroll
    for (int st=0; st<16; ++st){
      int c = dg*32 + st*2 + hh;             // 16B chunk index within K row
      bf16x8 kf = *(const bf16x8*)(KsB + ((ql>>4)*16 + (c>>2))*1024 + (c&3)*256 + (ql&15)*16);
      sc = __builtin_amdgcn_mfma_f32_32x32x16_bf16(kf, qf[st], sc, 0,0,0);
    }

    // exchange partial scores with dg-partner (w^1): conflict-free lane*16 layout
    char* Xw = Xch + w*4096;
    #pragma unroll
    for (int i=0;i<4;i++){
      f32x4 v;
      #pragma unroll
      for (int j=0;j<4;j++) v[j] = sc[4*i+j];
      *(f32x4*)(Xw + i*1024 + lane*16) = v;
    }
    asm volatile("s_waitcnt lgkmcnt(0)" ::: "memory");
    __builtin_amdgcn_sched_barrier(0);
    __builtin_amdgcn_s_barrier();            // B3: partials visible
    __builtin_amdgcn_sched_barrier(0);

    // full scores + fixed-reference softmax (per-lane, q = ql; keys in regs)
    char* Xp = Xch + (w^1)*4096;
    float pr[16];
    bool spec = (t >= NDENSE);
    int tbase = spec ? (j0 + (t-NDENSE)*32) : 0;
    #pragma unroll
    for (int i=0;i<4;i++){
      f32x4 v = *(const f32x4*)(Xp + i*1024 + lane*16);
      #pragma unroll
      for (int j=0;j<4;j++){
        int r = 4*i+j;
        float s = sc[r] + v[j];
        float pe = exp2f(s*C1 + C0);
        if (spec){
          int jk = tbase + (r&3) + 8*(r>>2) + 4*hh;
          bool ok = (jk>=0) & (jk<Shalf) & ((jk==iq) | (jk==tgt));
          pe = ok ? pe : 0.f;
        }
        pr[r] = pe;
        lp += pe;
      }
    }

    // P -> bf16 A-frags: cvt_pk pairs + permlane32_swap half exchange
    union { unsigned int u[4]; bf16x8 v; } pa0, pa1;
    {
      unsigned int X, Y;
      asm("v_cvt_pk_bf16_f32 %0, %1, %2" : "=v"(X) : "v"(pr[0]),  "v"(pr[1]));
      asm("v_cvt_pk_bf16_f32 %0, %1, %2" : "=v"(Y) : "v"(pr[4]),  "v"(pr[5]));
      asm("v_permlane32_swap_b32 %0, %1" : "+v"(X), "+v"(Y));
      pa0.u[0] = X; pa0.u[2] = Y;
      asm("v_cvt_pk_bf16_f32 %0, %1, %2" : "=v"(X) : "v"(pr[2]),  "v"(pr[3]));
      asm("v_cvt_pk_bf16_f32 %0, %1, %2" : "=v"(Y) : "v"(pr[6]),  "v"(pr[7]));
      asm("v_permlane32_swap_b32 %0, %1" : "+v"(X), "+v"(Y));
      pa0.u[1] = X; pa0.u[3] = Y;
      asm("v_cvt_pk_bf16_f32 %0, %1, %2" : "=v"(X) : "v"(pr[8]),  "v"(pr[9]));
      asm("v_cvt_pk_bf16_f32 %0, %1, %2" : "=v"(Y) : "v"(pr[12]), "v"(pr[13]));
      asm("v_permlane32_swap_b32 %0, %1" : "+v"(X), "+v"(Y));
      pa1.u[0] = X; pa1.u[2] = Y;
      asm("v_cvt_pk_bf16_f32 %0, %1, %2" : "=v"(X) : "v"(pr[10]), "v"(pr[11]));
      asm("v_cvt_pk_bf16_f32 %0, %1, %2" : "=v"(Y) : "v"(pr[14]), "v"(pr[15]));
      asm("v_permlane32_swap_b32 %0, %1" : "+v"(X), "+v"(Y));
      pa1.u[1] = X; pa1.u[3] = Y;
    }

    // PV: O[q][d] += P · V^T over this wave's 256 d (8 d-tiles x 2 key-steps)
    #pragma unroll
    for (int dt=0; dt<8; ++dt){
      int bi = dg*16 + dt*2 + ((lane>>4)&1);
      bf16x8 vf0 = *(const bf16x8*)(VsB + bi*1024 + hh*256 + (lane&15)*16);
      acc[dt] = __builtin_amdgcn_mfma_f32_32x32x16_bf16(pa0.v, vf0, acc[dt], 0,0,0);
      bf16x8 vf1 = *(const bf16x8*)(VsB + bi*1024 + (2+hh)*256 + (lane&15)*16);
      acc[dt] = __builtin_amdgcn_mfma_f32_32x32x16_bf16(pa1.v, vf1, acc[dt], 0,0,0);
    }
  }

  // epilogue: row sums (pair-sum + broadcast), normalize, head-mean via atomics
  float lpq = lp + __shfl_xor(lp, 32);
  #pragma unroll
  for (int r=0;r<16;++r){
    int qrow = (r&3) + 8*(r>>2) + 4*hh;
    float inv = 0.125f / __shfl(lpq, qrow);
    int orow = b*Sdim + 2*(i0 + qg*32 + qrow) + p;
    float* op = out + (size_t)orow*Ddim + dg*256 + ql;
    #pragma unroll
    for (int dt=0; dt<8; ++dt)
      atomicAdd(op + dt*32, acc[dt][r]*inv);
  }
}

extern "C" void kernel_launch(void* const* d_in, const int* in_sizes, int n_in,
                              void* d_out, int out_size, void* d_ws, size_t ws_size,
                              hipStream_t stream)
{
  (void)in_sizes; (void)n_in;
  const float* x  = (const float*)d_in[0];
  const float* Wq = (const float*)d_in[1];
  const float* Wk = (const float*)d_in[2];
  const float* Wv = (const float*)d_in[3];
  float* out = (float*)d_out;

  const size_t xb_bytes = (size_t)Mdim*Ddim*2;        // 8 MB
  const size_t wt_bytes = (size_t)3*Hdim*Ddim*Ddim*2; // 12.6 MB
  const size_t per_head = (size_t)Mdim*Ddim*2;        // 8.4 MB

  int g = 8;
  while (g > 1 && xb_bytes + wt_bytes + 3*(size_t)g*per_head > ws_size) g >>= 1;

  unsigned short* xb  = (unsigned short*)d_ws;
  unsigned short* Wt  = (unsigned short*)((char*)d_ws + xb_bytes);
  unsigned short* Qb  = (unsigned short*)((char*)d_ws + xb_bytes + wt_bytes);
  unsigned short* Kb  = Qb + (size_t)g*Mdim*Ddim;
  unsigned short* Vtb = Kb + (size_t)g*Mdim*Ddim;

  hipMemsetAsync(d_out, 0, (size_t)out_size*sizeof(float), stream);
  cvt_x<<<dim3(Mdim*Ddim/8/256), dim3(256), 0, stream>>>(x, xb, Mdim*Ddim/8);
  twk<<<dim3(Ddim/32, Ddim/32, 3*Hdim), dim3(32,8), 0, stream>>>(Wq, Wk, Wv, Wt);

  for (int h0 = 0; h0 < Hdim; h0 += g){
    proj<<<dim3(Mdim/128, 12*g), dim3(256), 0, stream>>>(xb, Wt, Qb, Kb, Vtb, h0, g);
    attn<<<dim3(g*Bdim*2, Shalf/128 /*qc=8*/), dim3(512), 0, stream>>>(Qb, Kb, Vtb, out);
  }
}

// Round 14
// 487.268 us; speedup vs baseline: 1.2761x; 1.1514x over previous
//
#include <hip/hip_runtime.h>
#include <stdint.h>

#define Bdim 4
#define Sdim 2048
#define Ddim 512
#define Hdim 8
#define Mdim (Bdim*Sdim)   // 8192
#define Shalf 1024

typedef __attribute__((ext_vector_type(8))) short bf16x8;
typedef __attribute__((ext_vector_type(4))) float f32x4;
typedef __attribute__((ext_vector_type(16))) float f32x16;
typedef __attribute__((ext_vector_type(4))) int i32x4;

#define SCALE 0.044194173824159216f   // 1/sqrt(512)
#define LOG2E 1.4426950408889634f

__device__ __forceinline__ unsigned short f2bf(float f){
  union { float f; unsigned int u; } v; v.f = f;
  unsigned int u = v.u + 0x7FFFu + ((v.u >> 16) & 1u);   // RNE
  return (unsigned short)(u >> 16);
}

__device__ __forceinline__ void gl_lds16(const void* g, void* l){
  __builtin_amdgcn_global_load_lds(
      (const __attribute__((address_space(1))) unsigned int*)g,
      (__attribute__((address_space(3))) unsigned int*)l, 16, 0, 0);
}

// parity permutation: row m (b*2048+s) -> b*2048 + (s&1)*1024 + (s>>1)
__device__ __forceinline__ int permrow(int m){
  return (m & ~2047) | ((m & 1) << 10) | ((m & 2047) >> 1);
}

// ---------------- prep: x fp32 -> bf16 ----------------
__global__ void cvt_x(const float* __restrict__ x, unsigned short* __restrict__ xb, int n8){
  int i = blockIdx.x*blockDim.x + threadIdx.x;
  if (i >= n8) return;
  const float4* p = (const float4*)x + (size_t)i*2;
  float4 a = p[0], b = p[1];
  union { unsigned short s[8]; i32x4 v; } o;
  o.s[0]=f2bf(a.x); o.s[1]=f2bf(a.y); o.s[2]=f2bf(a.z); o.s[3]=f2bf(a.w);
  o.s[4]=f2bf(b.x); o.s[5]=f2bf(b.y); o.s[6]=f2bf(b.z); o.s[7]=f2bf(b.w);
  ((i32x4*)xb)[i] = o.v;
}

// ---------------- prep: W fp32 [k][n] -> bf16 Wt [type*H+h][n][k] ----------------
__global__ void twk(const float* __restrict__ Wq, const float* __restrict__ Wk,
                    const float* __restrict__ Wv, unsigned short* __restrict__ Wt){
  __shared__ float t[32][33];
  int z = blockIdx.z;                       // type*H + h
  const float* W = (z < Hdim ? Wq : (z < 2*Hdim ? Wk : Wv)) + (size_t)(z % Hdim)*Ddim*Ddim;
  int n0 = blockIdx.x*32, k0 = blockIdx.y*32;
  #pragma unroll
  for (int i=0;i<4;i++){
    int k = k0 + threadIdx.y + i*8;
    t[threadIdx.y + i*8][threadIdx.x] = W[(size_t)k*Ddim + n0 + threadIdx.x];
  }
  __syncthreads();
  #pragma unroll
  for (int i=0;i<4;i++){
    int n = threadIdx.y + i*8;
    Wt[(size_t)z*Ddim*Ddim + (size_t)(n0+n)*Ddim + k0 + threadIdx.x] = f2bf(t[threadIdx.x][n]);
  }
}

// ---------------- projection: Q/K parity-permuted rows, V -> Vt [d][m'] ----------------
__launch_bounds__(256, 2)
__global__ void proj(const unsigned short* __restrict__ xb,
                     const unsigned short* __restrict__ Wt,
                     unsigned short* __restrict__ Qb,
                     unsigned short* __restrict__ Kb,
                     unsigned short* __restrict__ Vtb,
                     int h0, int g)
{
  __shared__ unsigned short smem[16640];    // A[0..4096) B[4096..8192) ; epilogue: [128][130]
  int tid = threadIdx.x, w = tid>>6, lane = tid&63;
  int wm = w>>1, wn = w&1;
  int y = blockIdx.y, g4 = 4*g;
  int type = y / g4; int rem = y - type*g4;
  int hrel = rem >> 2, nt = rem & 3;
  int m0 = blockIdx.x * 128, n0 = nt * 128;
  int l15 = lane&15, l4 = lane>>4;

  const unsigned short* Bsrc = Wt + (size_t)(type*Hdim + h0 + hrel)*Ddim*Ddim;

  f32x4 acc[4][4];
  #pragma unroll
  for (int i=0;i<4;i++)
    #pragma unroll
    for (int j=0;j<4;j++){ f32x4 z={0.f,0.f,0.f,0.f}; acc[i][j]=z; }

  for (int kt=0; kt<16; ++kt){
    int k0 = kt*32;
    #pragma unroll
    for (int i=0;i<2;i++){
      int row = i*64 + w*16 + (lane>>2);
      int cb  = lane&3;
      gl_lds16(xb   + (size_t)(m0+row)*Ddim + k0 + cb*8, (char*)smem + i*4096 + w*1024);
      gl_lds16(Bsrc + (size_t)(n0+row)*Ddim + k0 + cb*8, (char*)smem + 8192 + i*4096 + w*1024);
    }
    __syncthreads();
    bf16x8 af[4], bfr[4];
    #pragma unroll
    for (int i=0;i<4;i++){
      af[i]  = *(const bf16x8*)&smem[(wm*64 + i*16 + l15)*32 + l4*8];
      bfr[i] = *(const bf16x8*)&smem[4096 + (wn*64 + i*16 + l15)*32 + l4*8];
    }
    #pragma unroll
    for (int i=0;i<4;i++)
      #pragma unroll
      for (int j=0;j<4;j++)
        acc[i][j] = __builtin_amdgcn_mfma_f32_16x16x32_bf16(af[i], bfr[j], acc[i][j], 0,0,0);
    __syncthreads();
  }

  if (type < 2){
    unsigned short* Ob = (type==0 ? Qb : Kb) + (size_t)hrel*Mdim*Ddim;
    #pragma unroll
    for (int i=0;i<4;i++){
      int mb = m0 + wm*64 + i*16 + (l4<<2);
      #pragma unroll
      for (int j=0;j<4;j++){
        int col = n0 + wn*64 + j*16 + l15;
        #pragma unroll
        for (int r=0;r<4;r++)
          Ob[(size_t)permrow(mb + r)*Ddim + col] = f2bf(acc[i][j][r]);
      }
    }
  } else {
    // bounce-transpose tile through LDS, write Vt[d][m'] with parity-split columns
    #pragma unroll
    for (int i=0;i<4;i++){
      int ml = wm*64 + i*16 + (l4<<2);
      #pragma unroll
      for (int j=0;j<4;j++){
        int nl = wn*64 + j*16 + l15;
        #pragma unroll
        for (int r=0;r<4;r++)
          smem[(ml + r)*130 + nl] = f2bf(acc[i][j][r]);
      }
    }
    __syncthreads();
    unsigned short* Ovt = Vtb + (size_t)hrel*Ddim*Mdim;
    int bb  = m0 >> 11;
    int ib0 = (m0 & 2047) >> 1;     // i-base within parity block (64 i per tile)
    #pragma unroll
    for (int c=0;c<8;c++){
      int nl = c*16 + (tid>>4);     // d-local 0..127
      int il = (tid&15)*4;          // i-local 0..60 step 4
      #pragma unroll
      for (int pp=0; pp<2; pp++){
        union { unsigned short s[4]; uint2 v; } pk;
        #pragma unroll
        for (int ii=0;ii<4;ii++) pk.s[ii] = smem[(2*(il+ii)+pp)*130 + nl];
        *(uint2*)&Ovt[(size_t)(n0+nl)*Mdim + bb*Sdim + pp*Shalf + ib0 + il] = pk.v;
      }
    }
  }
}

// ---------------- staging (8 waves, bi = w*4+jj, 8 loads/wave) ----------------
__device__ __forceinline__ void stage_dense(const unsigned short* Kbase, int krow0,
                                            const unsigned short* Vblk, int vcol0,
                                            char* KsB, char* VsB, int w, int lane)
{
  int l15 = lane&15, l4 = lane>>4;
  #pragma unroll
  for (int jj=0;jj<4;jj++){
    int bi = w*4 + jj;
    int row = krow0 + ((bi>>4)<<4) + l15;
    int g   = ((bi&15)<<2) + l4;
    gl_lds16(Kbase + ((size_t)row<<9) + g*8, KsB + bi*1024);
    int d   = (bi<<4) + l15;
    int col = vcol0 + l4*8;
    gl_lds16(Vblk + ((size_t)d<<13) + col, VsB + bi*1024);
  }
}
__device__ __forceinline__ void stage_spec(const unsigned short* Kbase, int krow0,
                                           const unsigned short* Vblk, int vcol0,
                                           char* KsB, char* VsB, int w, int lane)
{
  int l15 = lane&15, l4 = lane>>4;
  #pragma unroll
  for (int jj=0;jj<4;jj++){
    int bi = w*4 + jj;
    int row = krow0 + ((bi>>4)<<4) + l15;
    row = row < 0 ? 0 : (row > Shalf-1 ? Shalf-1 : row);
    int g   = ((bi&15)<<2) + l4;
    gl_lds16(Kbase + ((size_t)row<<9) + g*8, KsB + bi*1024);
    int d   = (bi<<4) + l15;
    int col = vcol0 + l4*8;
    col = col < 0 ? 0 : (col > Shalf-8 ? Shalf-8 : col);
    gl_lds16(Vblk + ((size_t)d<<13) + col, VsB + bi*1024);
  }
}

// ---------------- flash attention: 32x32 swapped-QK^T, d-split waves -------------
// 2-barrier loop: K single-buffered (restaged after B3 proves all QK reads done),
// V triple-buffered (stage V(t+1) never collides with PV(t) or PV(t-1) reads),
// staging issued between B3 and softmax so it overlaps SM+PV.
#define NDENSE 32
#define NSPEC 5
#define NT (NDENSE + NSPEC)

__launch_bounds__(512, 2)
__global__ void attn(const unsigned short* __restrict__ Qb,
                     const unsigned short* __restrict__ Kb,
                     const unsigned short* __restrict__ Vtb,
                     float* __restrict__ out)
{
  __shared__ char lds[163840];   // K 32K | V tri-buf 96K | Xch 32K
  int tid = threadIdx.x, w = tid>>6, lane = tid&63;
  int qg = w>>1, dg = w&1;
  int ql = lane&31, hh = lane>>5;
  // grid = (z, qc): linear id = z + 64*qc -> XCD = z%8
  int z  = blockIdx.x;              // ((h*4+b)*2+p)
  int qc = blockIdx.y;              // 0..7 (128 queries each)
  int p  = z & 1; int zb = z >> 1; int b = zb & 3; int hd = zb >> 2;

  const unsigned short* Qp    = Qb + (size_t)hd*Mdim*Ddim + (size_t)(b*Sdim + p*Shalf)*Ddim;
  const unsigned short* Ksame = Kb + (size_t)hd*Mdim*Ddim + (size_t)(b*Sdim + p*Shalf)*Ddim;
  const unsigned short* Kopp  = Kb + (size_t)hd*Mdim*Ddim + (size_t)(b*Sdim + (1-p)*Shalf)*Ddim;
  const unsigned short* Vt    = Vtb + (size_t)hd*Ddim*Mdim;
  int csame = b*Sdim + p*Shalf;
  int copp  = b*Sdim + (1-p)*Shalf;
  int i0 = qc*128;
  int j0 = i0 - 32 + 32*p;          // parity-trimmed 32-aligned neighbor-window base

  const float C1 = SCALE*LOG2E;
  const float C0 = -4.0f*LOG2E;     // fixed softmax reference M=4 (scores*SCALE <~ 1.6)

  // Q fragments (B operand): rows q = i0+qg*32+ql, d = dg*256 + st*16 + hh*8 + j
  bf16x8 qf[16];
  {
    const unsigned short* qr = Qp + (size_t)(i0 + qg*32 + ql)*Ddim + dg*256 + hh*8;
    #pragma unroll
    for (int st=0; st<16; ++st) qf[st] = *(const bf16x8*)(qr + st*16);
  }

  f32x16 acc[8];
  #pragma unroll
  for (int dt=0; dt<8; ++dt)
    #pragma unroll
    for (int j=0; j<16; ++j) acc[dt][j] = 0.f;
  float lpp[4] = {0.f, 0.f, 0.f, 0.f};

  char* Kbuf = lds;
  char* Xch  = lds + 131072;
  int iq  = i0 + qg*32 + ql;
  int tgt = iq - 1 + 2*p;

  // prologue: stage tile 0 (dense): K(0) -> Kbuf, V(0) -> V-buf 0
  stage_dense(Ksame, 0, Vt + csame, 0, Kbuf, lds + 32768, w, lane);

  int vb = 0;
  for (int t=0; t<NT; ++t){
    char* VsB = lds + 32768 + vb*32768;

    asm volatile("s_waitcnt vmcnt(0)" ::: "memory");   // K(t),V(t) landed (issued last iter)
    __builtin_amdgcn_s_barrier();            // B2: tile t published
    __builtin_amdgcn_sched_barrier(0);

    // QK^T partial over this wave's 256 d:  S[key][q] = K · Q^T
    f32x16 sc;
    #pragma unroll
    for (int j=0; j<16; ++j) sc[j] = 0.f;
    #pragma unroll
    for (int st=0; st<16; ++st){
      int c = dg*32 + st*2 + hh;             // 16B chunk index within K row
      bf16x8 kf = *(const bf16x8*)(Kbuf + ((ql>>4)*16 + (c>>2))*1024 + (c&3)*256 + (ql&15)*16);
      sc = __builtin_amdgcn_mfma_f32_32x32x16_bf16(kf, qf[st], sc, 0,0,0);
    }

    // exchange partial scores with dg-partner (w^1): conflict-free lane*16 layout
    char* Xw = Xch + w*4096;
    #pragma unroll
    for (int i=0;i<4;i++){
      f32x4 v;
      #pragma unroll
      for (int j=0;j<4;j++) v[j] = sc[4*i+j];
      *(f32x4*)(Xw + i*1024 + lane*16) = v;
    }
    asm volatile("s_waitcnt lgkmcnt(0)" ::: "memory"); // own Xch writes + all QK reads drained
    __builtin_amdgcn_sched_barrier(0);
    __builtin_amdgcn_s_barrier();            // B3: partials visible; all waves' QK(t) done
    __builtin_amdgcn_sched_barrier(0);

    // stage tile t+1: K -> Kbuf (safe post-B3), V -> next tri-buf slot.
    // Overlaps softmax + PV below; drained by vmcnt(0) at next iter top.
    int vbn = vb + 1; if (vbn == 3) vbn = 0;
    if (t + 1 < NT){
      char* VsN = lds + 32768 + vbn*32768;
      if (t + 1 < NDENSE)
        stage_dense(Ksame, (t+1)*32, Vt + csame, (t+1)*32, Kbuf, VsN, w, lane);
      else {
        int tt = t + 1 - NDENSE;
        stage_spec(Kopp, j0 + tt*32, Vt + copp, j0 + tt*32, Kbuf, VsN, w, lane);
      }
    }

    // full scores + fixed-reference softmax (per-lane, q = ql; keys in regs)
    char* Xp = Xch + (w^1)*4096;
    float pr[16];
    bool spec = (t >= NDENSE);
    int tbase = spec ? (j0 + (t-NDENSE)*32) : 0;
    #pragma unroll
    for (int i=0;i<4;i++){
      f32x4 v = *(const f32x4*)(Xp + i*1024 + lane*16);
      #pragma unroll
      for (int j=0;j<4;j++){
        int r = 4*i+j;
        float s = sc[r] + v[j];
        float pe = exp2f(s*C1 + C0);
        if (spec){
          int jk = tbase + (r&3) + 8*(r>>2) + 4*hh;
          bool ok = (jk>=0) & (jk<Shalf) & ((jk==iq) | (jk==tgt));
          pe = ok ? pe : 0.f;
        }
        pr[r] = pe;
        lpp[i] += pe;
      }
    }

    // P -> bf16 A-frags: cvt_pk pairs + permlane32_swap half exchange
    union { unsigned int u[4]; bf16x8 v; } pa0, pa1;
    {
      unsigned int X, Y;
      asm("v_cvt_pk_bf16_f32 %0, %1, %2" : "=v"(X) : "v"(pr[0]),  "v"(pr[1]));
      asm("v_cvt_pk_bf16_f32 %0, %1, %2" : "=v"(Y) : "v"(pr[4]),  "v"(pr[5]));
      asm("v_permlane32_swap_b32 %0, %1" : "+v"(X), "+v"(Y));
      pa0.u[0] = X; pa0.u[2] = Y;
      asm("v_cvt_pk_bf16_f32 %0, %1, %2" : "=v"(X) : "v"(pr[2]),  "v"(pr[3]));
      asm("v_cvt_pk_bf16_f32 %0, %1, %2" : "=v"(Y) : "v"(pr[6]),  "v"(pr[7]));
      asm("v_permlane32_swap_b32 %0, %1" : "+v"(X), "+v"(Y));
      pa0.u[1] = X; pa0.u[3] = Y;
      asm("v_cvt_pk_bf16_f32 %0, %1, %2" : "=v"(X) : "v"(pr[8]),  "v"(pr[9]));
      asm("v_cvt_pk_bf16_f32 %0, %1, %2" : "=v"(Y) : "v"(pr[12]), "v"(pr[13]));
      asm("v_permlane32_swap_b32 %0, %1" : "+v"(X), "+v"(Y));
      pa1.u[0] = X; pa1.u[2] = Y;
      asm("v_cvt_pk_bf16_f32 %0, %1, %2" : "=v"(X) : "v"(pr[10]), "v"(pr[11]));
      asm("v_cvt_pk_bf16_f32 %0, %1, %2" : "=v"(Y) : "v"(pr[14]), "v"(pr[15]));
      asm("v_permlane32_swap_b32 %0, %1" : "+v"(X), "+v"(Y));
      pa1.u[1] = X; pa1.u[3] = Y;
    }

    // PV: O[q][d] += P · V^T over this wave's 256 d (8 d-tiles x 2 key-steps)
    #pragma unroll
    for (int dt=0; dt<8; ++dt){
      int bi = dg*16 + dt*2 + ((lane>>4)&1);
      bf16x8 vf0 = *(const bf16x8*)(VsB + bi*1024 + hh*256 + (lane&15)*16);
      acc[dt] = __builtin_amdgcn_mfma_f32_32x32x16_bf16(pa0.v, vf0, acc[dt], 0,0,0);
      bf16x8 vf1 = *(const bf16x8*)(VsB + bi*1024 + (2+hh)*256 + (lane&15)*16);
      acc[dt] = __builtin_amdgcn_mfma_f32_32x32x16_bf16(pa1.v, vf1, acc[dt], 0,0,0);
    }
    vb = vbn;
  }

  // epilogue: row sums (pair-sum + broadcast), normalize, head-mean via atomics
  float lp = (lpp[0] + lpp[1]) + (lpp[2] + lpp[3]);
  float lpq = lp + __shfl_xor(lp, 32);
  #pragma unroll
  for (int r=0;r<16;++r){
    int qrow = (r&3) + 8*(r>>2) + 4*hh;
    float inv = 0.125f / __shfl(lpq, qrow);
    int orow = b*Sdim + 2*(i0 + qg*32 + qrow) + p;
    float* op = out + (size_t)orow*Ddim + dg*256 + ql;
    #pragma unroll
    for (int dt=0; dt<8; ++dt)
      atomicAdd(op + dt*32, acc[dt][r]*inv);
  }
}

extern "C" void kernel_launch(void* const* d_in, const int* in_sizes, int n_in,
                              void* d_out, int out_size, void* d_ws, size_t ws_size,
                              hipStream_t stream)
{
  (void)in_sizes; (void)n_in;
  const float* x  = (const float*)d_in[0];
  const float* Wq = (const float*)d_in[1];
  const float* Wk = (const float*)d_in[2];
  const float* Wv = (const float*)d_in[3];
  float* out = (float*)d_out;

  const size_t xb_bytes = (size_t)Mdim*Ddim*2;        // 8 MB
  const size_t wt_bytes = (size_t)3*Hdim*Ddim*Ddim*2; // 12.6 MB
  const size_t per_head = (size_t)Mdim*Ddim*2;        // 8.4 MB

  int g = 8;
  while (g > 1 && xb_bytes + wt_bytes + 3*(size_t)g*per_head > ws_size) g >>= 1;

  unsigned short* xb  = (unsigned short*)d_ws;
  unsigned short* Wt  = (unsigned short*)((char*)d_ws + xb_bytes);
  unsigned short* Qb  = (unsigned short*)((char*)d_ws + xb_bytes + wt_bytes);
  unsigned short* Kb  = Qb + (size_t)g*Mdim*Ddim;
  unsigned short* Vtb = Kb + (size_t)g*Mdim*Ddim;

  hipMemsetAsync(d_out, 0, (size_t)out_size*sizeof(float), stream);
  cvt_x<<<dim3(Mdim*Ddim/8/256), dim3(256), 0, stream>>>(x, xb, Mdim*Ddim/8);
  twk<<<dim3(Ddim/32, Ddim/32, 3*Hdim), dim3(32,8), 0, stream>>>(Wq, Wk, Wv, Wt);

  for (int h0 = 0; h0 < Hdim; h0 += g){
    proj<<<dim3(Mdim/128, 12*g), dim3(256), 0, stream>>>(xb, Wt, Qb, Kb, Vtb, h0, g);
    attn<<<dim3(g*Bdim*2, Shalf/128 /*qc=8*/), dim3(512), 0, stream>>>(Qb, Kb, Vtb, out);
  }
}